// Round 4
// baseline (209.673 us; speedup 1.0000x reference)
//
#include <hip/hip_runtime.h>
#include <hip/hip_bf16.h>
#include <cstdint>

// SelfSimilarity: out[b,i,j] = softmax_j( -T * max(||x_i - x_j||^2, 0) )
// bf16 MFMA via norm expansion; ||x||^2 computed from ROUNDED bf16 values so
// the diagonal logit is exactly 0 => max logit is 0 => no online max needed.
// R4 (=R3 retry, type fix): single sweep, M=16 rows/block. B fragments loaded
// DIRECTLY from L2 (ws layout == MFMA fragment layout) -> no LDS staging, no
// j-loop barriers. P packed as __fp16 pairs (64 VGPRs) -> 3 blocks/CU.
// XCD-swizzled batches.

using bf16x8 = __attribute__((ext_vector_type(8))) short;
using f32x4  = __attribute__((ext_vector_type(4))) float;
using half2v = __attribute__((ext_vector_type(2))) __fp16;   // matches cvt_pkrtz return

#define TEMP   (1.0f / 13.544f)
#define LOG2E  1.4426950408889634f

// ---------------------------------------------------------------------------
// prep: fp32 -> bf16 (RNE) in MFMA-fragment layout + csq[row] = -T*log2e*||x_bf||^2
// ws bf16 layout: [b][group=row>>4][qblock=k>>3][r=row&15][8 elems]
//   -> uint4 index: (b*128+g)*256 + q*16 + r
// Block->batch mapping XCD-swizzled: batch = blk&7 (round-robin dispatch ->
// each XCD's L2 keeps its own batch's 512 KB slice warm for sim_kernel).
// ---------------------------------------------------------------------------
__global__ __launch_bounds__(256) void prep_kernel(
    const float* __restrict__ x, uint4* __restrict__ xbf, float* __restrict__ csq)
{
    const int t   = threadIdx.x;
    const int lr  = t >> 4;            // local row 0..15
    const int q   = t & 15;            // k-block of 8
    const int row = (blockIdx.x & 7) * 2048 + (blockIdx.x >> 3) * 16 + lr;

    const float* xp = x + (size_t)row * 128 + q * 8;
    float4 a0 = *(const float4*)(xp);
    float4 a1 = *(const float4*)(xp + 4);
    float v[8] = {a0.x, a0.y, a0.z, a0.w, a1.x, a1.y, a1.z, a1.w};

    unsigned u[8];
    float s = 0.f;
#pragma unroll
    for (int e = 0; e < 8; ++e) {
        unsigned ui = __float_as_uint(v[e]);
        unsigned r  = (ui + 0x7FFFu + ((ui >> 16) & 1u)) >> 16;   // RNE to bf16
        u[e] = r;
        float d = __uint_as_float(r << 16);                        // decoded value
        s += d * d;                                                // norm of ROUNDED vec
    }
    uint4 pack;
    pack.x = u[0] | (u[1] << 16);
    pack.y = u[2] | (u[3] << 16);
    pack.z = u[4] | (u[5] << 16);
    pack.w = u[6] | (u[7] << 16);

    const int b  = row >> 11;
    const int g  = (row >> 4) & 127;
    const int rr = row & 15;
    xbf[(b * 128 + g) * 256 + q * 16 + rr] = pack;

#pragma unroll
    for (int m = 1; m < 16; m <<= 1) s += __shfl_xor(s, m, 64);
    if (q == 0) csq[row] = s * (-TEMP * LOG2E);
}

// ---------------------------------------------------------------------------
// main: per workgroup, M=16 rows x all 2048 cols, single sweep, no LDS tiles.
// 4 waves split each 128-col j-tile (wave w -> cols w*32..w*32+31).
// A fragments pinned; B fragments streamed from L2 (frag-layout ws).
// P packed __fp16 pairs in registers (16 tiles x 4 = 64 VGPRs); row sums
// inline; cross-lane/wave reduce; pure store burst of f32(P) * inv.
// logit2 = log2e*(-T*dist) = C2L*dot + csq_i + csq_j, clamped <= 0.
// ---------------------------------------------------------------------------
__global__ __launch_bounds__(256, 3) void sim_kernel(
    const uint4* __restrict__ xbf, const float* __restrict__ csq, float* __restrict__ out)
{
    const int blk  = blockIdx.x;
    const int b    = blk & 7;             // XCD-swizzled batch
    const int i0   = (blk >> 3) * 16;     // row tile within batch
    const int tid  = threadIdx.x;
    const int w    = tid >> 6;
    const int lane = tid & 63;
    const int quad = lane >> 4;
    const int l15  = lane & 15;

    __shared__ float lsSum[4][16];
    __shared__ __align__(16) float lsInv[16];

    const uint4* xbb  = xbf + (size_t)b * (128 * 256);
    const float* csqb = csq + b * 2048;

    // A fragments: rows i0..i0+15, all K. lane holds row l15, k-block quad per k4.
    bf16x8 afrag[4];
#pragma unroll
    for (int k4 = 0; k4 < 4; ++k4) {
        uint4 vv = xbb[(i0 >> 4) * 256 + (k4 * 4 + quad) * 16 + l15];
        afrag[k4] = __builtin_bit_cast(bf16x8, vv);
    }

    float csqi[4];
    {
        float4 vv = *(const float4*)(csqb + i0 + quad * 4);
        csqi[0] = vv.x; csqi[1] = vv.y; csqi[2] = vv.z; csqi[3] = vv.w;
    }

    const float C2L = 2.0f * TEMP * LOG2E;
    const int   c0  = w * 32;

    half2v P[16][4];
    float  sum_[4] = {};

#pragma unroll
    for (int jt = 0; jt < 16; ++jt) {
        // B fragments for this wave's two 16-col groups, straight from L2.
        const uint4* bg = xbb + (jt * 8 + w * 2) * 256;
        uint4 b0[4], b1[4];
#pragma unroll
        for (int k4 = 0; k4 < 4; ++k4) {
            b0[k4] = bg[(k4 * 4 + quad) * 16 + l15];
            b1[k4] = bg[256 + (k4 * 4 + quad) * 16 + l15];
        }
        const float csqj0 = csqb[jt * 128 + c0 + l15];
        const float csqj1 = csqb[jt * 128 + c0 + 16 + l15];

        f32x4 acc0 = {}, acc1 = {};
#pragma unroll
        for (int k4 = 0; k4 < 4; ++k4) {
            acc0 = __builtin_amdgcn_mfma_f32_16x16x32_bf16(
                       afrag[k4], __builtin_bit_cast(bf16x8, b0[k4]), acc0, 0, 0, 0);
            acc1 = __builtin_amdgcn_mfma_f32_16x16x32_bf16(
                       afrag[k4], __builtin_bit_cast(bf16x8, b1[k4]), acc1, 0, 0, 0);
        }

#pragma unroll
        for (int r = 0; r < 4; ++r) {
            float lg0 = fminf(fmaf(C2L, acc0[r], csqi[r] + csqj0), 0.f);
            float lg1 = fminf(fmaf(C2L, acc1[r], csqi[r] + csqj1), 0.f);
            float p0  = exp2f(lg0);
            float p1  = exp2f(lg1);
            sum_[r] += p0 + p1;
            P[jt][r] = __builtin_amdgcn_cvt_pkrtz(p0, p1);   // pack (col, col+16)
        }
    }

    // reduce sums: over the 16-lane col groups (bits 0..3), then across waves
#pragma unroll
    for (int r = 0; r < 4; ++r) {
        float s = sum_[r];
        s += __shfl_xor(s, 1, 64);
        s += __shfl_xor(s, 2, 64);
        s += __shfl_xor(s, 4, 64);
        s += __shfl_xor(s, 8, 64);
        sum_[r] = s;
    }
    if (l15 == 0) {
#pragma unroll
        for (int r = 0; r < 4; ++r) lsSum[w][quad * 4 + r] = sum_[r];
    }
    __syncthreads();
    if (tid < 16) {
        float tot = lsSum[0][tid] + lsSum[1][tid] + lsSum[2][tid] + lsSum[3][tid];
        lsInv[tid] = 1.0f / tot;
    }
    __syncthreads();

    float inv_[4];
    {
        float4 vv = *(const float4*)(&lsInv[quad * 4]);
        inv_[0] = vv.x; inv_[1] = vv.y; inv_[2] = vv.z; inv_[3] = vv.w;
    }

    // store burst: per inst, 4 rows x 64 B contiguous segments; r outer so each
    // row sweeps sequentially through L2.
    float* outrow = out + ((size_t)b * 2048 + i0) * 2048;
#pragma unroll
    for (int r = 0; r < 4; ++r) {
        float* op = outrow + (size_t)(quad * 4 + r) * 2048 + c0 + l15;
#pragma unroll
        for (int jt = 0; jt < 16; ++jt) {
            op[jt * 128]      = (float)P[jt][r].x * inv_[r];
            op[jt * 128 + 16] = (float)P[jt][r].y * inv_[r];
        }
    }
}

extern "C" void kernel_launch(void* const* d_in, const int* in_sizes, int n_in,
                              void* d_out, int out_size, void* d_ws, size_t ws_size,
                              hipStream_t stream) {
    const float* x   = (const float*)d_in[0];
    float*       out = (float*)d_out;
    // ws: [0, 4MB) packed bf16 x; [4MB, 4MB+64KB) csq. Needs ~4.26 MB of ws.
    uint4* xbf = (uint4*)d_ws;
    float* csq = (float*)((char*)d_ws + (size_t)4 * 1024 * 1024);

    prep_kernel<<<1024, 256, 0, stream>>>(x, xbf, csq);     // 16384 rows
    sim_kernel<<<1024, 256, 0, stream>>>(xbf, csq, out);    // 8 batches x 128 row-tiles
}

// Round 5
// 206.549 us; speedup vs baseline: 1.0151x; 1.0151x over previous
//
#include <hip/hip_runtime.h>
#include <hip/hip_bf16.h>
#include <cstdint>

// SelfSimilarity: out[b,i,j] = softmax_j( -T * max(||x_i - x_j||^2, 0) )
// bf16 MFMA via norm expansion; ||x||^2 computed from ROUNDED bf16 values so
// the diagonal logit is exactly 0 => max logit is 0 => no online max needed.
// R5: operand-swapped MFMA so each lane owns one output ROW (lane&15) and 4
// consecutive cols per acc reg. Row-sum becomes lane-local; inv is a lane
// scalar. Epilogue repacks through wave-private LDS (no barriers) so every
// global store inst writes 8 rows x 128B full-line segments -> kills the
// 2.07x HBM write amplification measured in R4.

using bf16x8 = __attribute__((ext_vector_type(8))) short;
using f32x4  = __attribute__((ext_vector_type(4))) float;
using half2v = __attribute__((ext_vector_type(2))) __fp16;

#define TEMP   (1.0f / 13.544f)
#define LOG2E  1.4426950408889634f

// ---------------------------------------------------------------------------
// prep: fp32 -> bf16 (RNE) in MFMA-fragment layout + csq[row] = -T*log2e*||x_bf||^2
// ws bf16 layout: [b][group=row>>4][qblock=k>>3][r=row&15][8 elems]
//   -> uint4 index: (b*128+g)*256 + q*16 + r
// ---------------------------------------------------------------------------
__global__ __launch_bounds__(256) void prep_kernel(
    const float* __restrict__ x, uint4* __restrict__ xbf, float* __restrict__ csq)
{
    const int t   = threadIdx.x;
    const int lr  = t >> 4;            // local row 0..15
    const int q   = t & 15;            // k-block of 8
    const int row = (blockIdx.x & 7) * 2048 + (blockIdx.x >> 3) * 16 + lr;

    const float* xp = x + (size_t)row * 128 + q * 8;
    float4 a0 = *(const float4*)(xp);
    float4 a1 = *(const float4*)(xp + 4);
    float v[8] = {a0.x, a0.y, a0.z, a0.w, a1.x, a1.y, a1.z, a1.w};

    unsigned u[8];
    float s = 0.f;
#pragma unroll
    for (int e = 0; e < 8; ++e) {
        unsigned ui = __float_as_uint(v[e]);
        unsigned r  = (ui + 0x7FFFu + ((ui >> 16) & 1u)) >> 16;   // RNE to bf16
        u[e] = r;
        float d = __uint_as_float(r << 16);                        // decoded value
        s += d * d;                                                // norm of ROUNDED vec
    }
    uint4 pack;
    pack.x = u[0] | (u[1] << 16);
    pack.y = u[2] | (u[3] << 16);
    pack.z = u[4] | (u[5] << 16);
    pack.w = u[6] | (u[7] << 16);

    const int b  = row >> 11;
    const int g  = (row >> 4) & 127;
    const int rr = row & 15;
    xbf[(b * 128 + g) * 256 + q * 16 + rr] = pack;

#pragma unroll
    for (int m = 1; m < 16; m <<= 1) s += __shfl_xor(s, m, 64);
    if (q == 0) csq[row] = s * (-TEMP * LOG2E);
}

// ---------------------------------------------------------------------------
// main: per workgroup, M=16 rows x all 2048 cols, single sweep, no LDS tiles
// for the GEMM (fragments straight from L2; ws layout == fragment layout).
// Operand-swapped MFMA: D[m'][n'] with n' = lane&15 = OUR ROW, m' = quad*4+reg
// = col-within-16-group. Wave w covers cols w*32 + {0..15, 16..31} per j-tile.
// P packed __fp16 pairs (64 VGPRs). After sums: scale by lane-scalar inv,
// repack via wave-private LDS, store dwordx4 full-line segments.
// ---------------------------------------------------------------------------
__global__ __launch_bounds__(256, 3) void sim_kernel(
    const uint4* __restrict__ xbf, const float* __restrict__ csq, float* __restrict__ out)
{
    const int blk  = blockIdx.x;
    const int b    = blk & 7;             // XCD-swizzled batch
    const int i0   = (blk >> 3) * 16;     // row tile within batch
    const int tid  = threadIdx.x;
    const int w    = tid >> 6;
    const int lane = tid & 63;
    const int quad = lane >> 4;
    const int l15  = lane & 15;

    // wave-private repack tiles: [16 rows][36 words] per wave (pad 32->36
    // keeps b128 ops 2-way max on banks). 4*576*4 = 9216 B.
    __shared__ __align__(16) float lsT[4 * 576];
    __shared__ float lsSum[4][16];
    __shared__ __align__(16) float lsInv[16];

    const uint4* xbb  = xbf + (size_t)b * (128 * 256);
    const float* csqb = csq + b * 2048;

    // i-fragment: rows i0..i0+15, all K. lane holds row l15, k-chunk per k4.
    bf16x8 ifrag[4];
#pragma unroll
    for (int k4 = 0; k4 < 4; ++k4) {
        uint4 vv = xbb[(i0 >> 4) * 256 + (k4 * 4 + quad) * 16 + l15];
        ifrag[k4] = __builtin_bit_cast(bf16x8, vv);
    }

    const float csqi = csqb[i0 + l15];          // lane-scalar: our row's term
    const float C2L  = 2.0f * TEMP * LOG2E;
    const int   c0   = w * 32;

    half2v P[16][4];
    float  sum_ = 0.f;

#pragma unroll
    for (int jt = 0; jt < 16; ++jt) {
        // j-fragments for this wave's two 16-col groups, straight from L2.
        const uint4* bg = xbb + (jt * 8 + w * 2) * 256;
        uint4 j0f[4], j1f[4];
#pragma unroll
        for (int k4 = 0; k4 < 4; ++k4) {
            j0f[k4] = bg[(k4 * 4 + quad) * 16 + l15];
            j1f[k4] = bg[256 + (k4 * 4 + quad) * 16 + l15];
        }
        // per-reg col terms: cols jt*128 + c0 (+16) + quad*4 + r
        float4 cj0 = *(const float4*)(csqb + jt * 128 + c0 + quad * 4);
        float4 cj1 = *(const float4*)(csqb + jt * 128 + c0 + 16 + quad * 4);

        f32x4 acc0 = {}, acc1 = {};
#pragma unroll
        for (int k4 = 0; k4 < 4; ++k4) {
            acc0 = __builtin_amdgcn_mfma_f32_16x16x32_bf16(
                       __builtin_bit_cast(bf16x8, j0f[k4]), ifrag[k4], acc0, 0, 0, 0);
            acc1 = __builtin_amdgcn_mfma_f32_16x16x32_bf16(
                       __builtin_bit_cast(bf16x8, j1f[k4]), ifrag[k4], acc1, 0, 0, 0);
        }

        const float cj0a[4] = {cj0.x, cj0.y, cj0.z, cj0.w};
        const float cj1a[4] = {cj1.x, cj1.y, cj1.z, cj1.w};
#pragma unroll
        for (int r = 0; r < 4; ++r) {
            float lg0 = fminf(fmaf(C2L, acc0[r], csqi + cj0a[r]), 0.f);
            float lg1 = fminf(fmaf(C2L, acc1[r], csqi + cj1a[r]), 0.f);
            float p0  = exp2f(lg0);
            float p1  = exp2f(lg1);
            sum_ += p0 + p1;
            P[jt][r] = __builtin_amdgcn_cvt_pkrtz(p0, p1);  // (col, col+16)
        }
    }

    // row sum: lane-local partial covers cols {quad*4+r} of every 16-group;
    // combine across quads (lanes 16 apart), then across waves via LDS.
    sum_ += __shfl_xor(sum_, 16, 64);
    sum_ += __shfl_xor(sum_, 32, 64);
    if (lane < 16) lsSum[w][l15] = sum_;
    __syncthreads();
    if (tid < 16) {
        float tot = lsSum[0][tid] + lsSum[1][tid] + lsSum[2][tid] + lsSum[3][tid];
        lsInv[tid] = 1.0f / tot;
    }
    __syncthreads();
    const float inv = lsInv[l15];               // lane-scalar: our row's 1/Z

    // epilogue: per j-tile, scale + repack through wave-private LDS, then
    // store dwordx4: each inst = 8 rows x 128 B aligned full-line segments.
    float* const lt = &lsT[w * 576];
    const int wr0 = l15 * 36 + quad * 4;            // write: row l15, colq quad
    const int rd0 = (lane >> 3) * 36 + (lane & 7) * 4;  // read: row l>>3
    float* outp = out + ((size_t)b * 2048 + i0 + (lane >> 3)) * 2048 + c0 + (lane & 7) * 4;

#pragma unroll
    for (int jt = 0; jt < 16; ++jt) {
        f32x4 w0, w1;
#pragma unroll
        for (int r = 0; r < 4; ++r) {
            w0[r] = (float)P[jt][r].x * inv;
            w1[r] = (float)P[jt][r].y * inv;
        }
        *(f32x4*)(&lt[wr0])      = w0;   // cols quad*4..+3
        *(f32x4*)(&lt[wr0 + 16]) = w1;   // cols 16+quad*4..+3
        f32x4 s0 = *(const f32x4*)(&lt[rd0]);            // rows 0..7
        f32x4 s1 = *(const f32x4*)(&lt[rd0 + 8 * 36]);   // rows 8..15
        *(f32x4*)(outp + jt * 128)                      = s0;
        *(f32x4*)(outp + (size_t)8 * 2048 + jt * 128)   = s1;
    }
}

extern "C" void kernel_launch(void* const* d_in, const int* in_sizes, int n_in,
                              void* d_out, int out_size, void* d_ws, size_t ws_size,
                              hipStream_t stream) {
    const float* x   = (const float*)d_in[0];
    float*       out = (float*)d_out;
    // ws: [0, 4MB) packed bf16 x; [4MB, 4MB+64KB) csq. Needs ~4.26 MB of ws.
    uint4* xbf = (uint4*)d_ws;
    float* csq = (float*)((char*)d_ws + (size_t)4 * 1024 * 1024);

    prep_kernel<<<1024, 256, 0, stream>>>(x, xbf, csq);     // 16384 rows
    sim_kernel<<<1024, 256, 0, stream>>>(xbf, csq, out);    // 8 batches x 128 row-tiles
}